// Round 5
// baseline (384.058 us; speedup 1.0000x reference)
//
#include <hip/hip_runtime.h>

#define SEQ 4096
#define HIDDEN 2048
#define NHEADS 16
#define HDIM 128
#define QBLK 128
#define WQ 32
#define KVB 64

typedef float f32x4 __attribute__((ext_vector_type(4)));
typedef __bf16 bf16x8 __attribute__((ext_vector_type(8)));
typedef unsigned int u32x4 __attribute__((ext_vector_type(4)));
typedef unsigned int u32x2 __attribute__((ext_vector_type(2)));
typedef unsigned short u16x8 __attribute__((ext_vector_type(8)));
typedef unsigned short u16x4 __attribute__((ext_vector_type(4)));
typedef unsigned short u16;

// 1/sqrt(128) * log2(e)  (softmax in exp2 domain)
#define SCL2 0.12751747456918851f
// log2(10000)/64
#define RLOG 0.2076205059304601f

__device__ __forceinline__ u16 f2bf(float f) {
  unsigned u = __float_as_uint(f);
  unsigned r = 0x7fffu + ((u >> 16) & 1u);
  return (u16)((u + r) >> 16);
}
__device__ __forceinline__ float bf2f(u16 u) {
  return __uint_as_float(((unsigned)u) << 16);
}
__device__ __forceinline__ unsigned cvtpk(float a, float b) {
  unsigned r;
  asm volatile("v_cvt_pk_bf16_f32 %0, %1, %2" : "=v"(r) : "v"(a), "v"(b));
  return r;
}

// async global->LDS, 16B per lane; dest = wave-uniform base + lane*16
__device__ __forceinline__ void gload16(const u16* g, u16* l) {
  __builtin_amdgcn_global_load_lds(
      (const __attribute__((address_space(1))) unsigned int*)g,
      (__attribute__((address_space(3))) unsigned int*)l, 16, 0, 0);
}

// chunk slot base within a head, for multi-chunk qtiles (q>=8); 72 slots/head
__device__ __forceinline__ int cumq(int q) {
  if (q < 16) return (q - 8) * 2;
  if (q < 24) return 16 + (q - 16) * 3;
  return 40 + (q - 24) * 4;
}

// ---------------- fp32 -> bf16 convert (all 5 inputs, one launch) ----------
__global__ __launch_bounds__(256) void cvt5(const float* __restrict__ X,
    const float* __restrict__ Wq, const float* __restrict__ Wk,
    const float* __restrict__ Wv, const float* __restrict__ Wo,
    u16* __restrict__ dst) {
  const size_t SH = (size_t)SEQ * HIDDEN, HH = (size_t)HIDDEN * HIDDEN;
  size_t i = ((size_t)blockIdx.x * 256 + threadIdx.x) * 8;
  const float* src; size_t off;
  if (i < SH) { src = X; off = i; }
  else if (i < SH + HH) { src = Wq; off = i - SH; }
  else if (i < SH + 2 * HH) { src = Wk; off = i - SH - HH; }
  else if (i < SH + 3 * HH) { src = Wv; off = i - SH - 2 * HH; }
  else { src = Wo; off = i - SH - 3 * HH; }
  float4 a = *reinterpret_cast<const float4*>(src + off);
  float4 b = *reinterpret_cast<const float4*>(src + off + 4);
  u16x8 o;
  o[0] = f2bf(a.x); o[1] = f2bf(a.y); o[2] = f2bf(a.z); o[3] = f2bf(a.w);
  o[4] = f2bf(b.x); o[5] = f2bf(b.y); o[6] = f2bf(b.z); o[7] = f2bf(b.w);
  *reinterpret_cast<u32x4*>(dst + i) = __builtin_bit_cast(u32x4, o);
}

// ---------------- fused QKV GEMM (+RoPE epilogue for Q,K) -------------------
__global__ __launch_bounds__(256, 3) void gemm_qkv(const u16* __restrict__ Xb,
    const u16* __restrict__ Wqb, const u16* __restrict__ Wkb,
    const u16* __restrict__ Wvb, u16* __restrict__ Qo, u16* __restrict__ Ko,
    u16* __restrict__ Vt) {
  __shared__ u16 As[2][128 * 32];
  __shared__ u16 Bs[2][128 * 32];
  const int wg = blockIdx.x;
  const int swz = (wg & 7) * 192 + (wg >> 3);   // 1536 = 8*192, bijective
  const int z = swz >> 9;
  const int rr_ = swz & 511;
  const u16 *A, *B;
  u16* C;
  int bm, bn, cst;
  if (z == 2) {
    A = Wvb; B = Xb; C = Vt;
    bm = (rr_ & 15) << 7; bn = (rr_ >> 4) << 7; cst = SEQ;
  } else {
    A = Xb; B = z ? Wkb : Wqb; C = z ? Ko : Qo;
    bm = (rr_ & 31) << 7; bn = (rr_ >> 5) << 7; cst = HIDDEN;
  }
  const int t = threadIdx.x, lane = t & 63, wave = t >> 6;
  const int lrow = lane & 15, lk = (lane >> 4) * 8;
  const int wr = wave * 32;
  const int r0 = t >> 2, c0 = (t & 3) * 8;

  f32x4 acc[2][8] = {};

#pragma unroll
  for (int is = 0; is < 2; ++is) {
    gload16(A + (size_t)(bm + is * 64 + r0) * HIDDEN + c0, &As[0][is * 2048 + t * 8]);
    gload16(B + (size_t)(bn + is * 64 + r0) * HIDDEN + c0, &Bs[0][is * 2048 + t * 8]);
  }
  __syncthreads();

  int p = 0;
  for (int kt = 0; kt < HIDDEN; kt += 32) {
    if (kt + 32 < HIDDEN) {
#pragma unroll
      for (int is = 0; is < 2; ++is) {
        gload16(A + (size_t)(bm + is * 64 + r0) * HIDDEN + kt + 32 + c0,
                &As[p ^ 1][is * 2048 + t * 8]);
        gload16(B + (size_t)(bn + is * 64 + r0) * HIDDEN + kt + 32 + c0,
                &Bs[p ^ 1][is * 2048 + t * 8]);
      }
    }
    bf16x8 af[2], bfv[8];
#pragma unroll
    for (int m = 0; m < 2; ++m)
      af[m] = __builtin_bit_cast(bf16x8,
          *reinterpret_cast<const u32x4*>(&As[p][(wr + m * 16 + lrow) * 32 + lk]));
#pragma unroll
    for (int n = 0; n < 8; ++n)
      bfv[n] = __builtin_bit_cast(bf16x8,
          *reinterpret_cast<const u32x4*>(&Bs[p][(n * 16 + lrow) * 32 + lk]));
#pragma unroll
    for (int n = 0; n < 8; ++n)
#pragma unroll
      for (int m = 0; m < 2; ++m)
        acc[m][n] = __builtin_amdgcn_mfma_f32_16x16x32_bf16(af[m], bfv[n], acc[m][n], 0, 0, 0);
    __syncthreads();
    p ^= 1;
  }

  const int rb = (lane >> 4) * 4;
  if (z < 2) {  // RoPE on f32 accumulator: lane holds col pairs (i, i+64)
#pragma unroll
    for (int m = 0; m < 2; ++m)
#pragma unroll
      for (int q = 0; q < 4; ++q) {
        const int s = bm + wr + m * 16 + rb + q;
#pragma unroll
        for (int n = 0; n < 4; ++n) {
          const int ii = n * 16 + lrow;
          float inv = exp2f((float)ii * -RLOG);
          float ang = (float)s * inv;
          float sn, cs;
          __sincosf(ang, &sn, &cs);
          float x1 = acc[m][n][q], x2 = acc[m][n + 4][q];
          acc[m][n][q] = x1 * cs - x2 * sn;
          acc[m][n + 4][q] = x2 * cs + x1 * sn;
        }
      }
  }
#pragma unroll
  for (int m = 0; m < 2; ++m)
#pragma unroll
    for (int n = 0; n < 8; ++n)
#pragma unroll
      for (int q = 0; q < 4; ++q)
        C[(size_t)(bm + wr + m * 16 + rb + q) * cst + bn + n * 16 + lrow] =
            f2bf(acc[m][n][q]);
}

// ---------------- output GEMM: out = Cb * Wo^T (f32 out) --------------------
__global__ __launch_bounds__(256, 3) void gemm_out(const u16* __restrict__ A,
    const u16* __restrict__ B, float* __restrict__ C) {
  __shared__ u16 As[2][128 * 32];
  __shared__ u16 Bs[2][128 * 32];
  const int wg = blockIdx.x;
  const int swz = (wg & 7) * 64 + (wg >> 3);    // 512 = 8*64
  const int bm = (swz & 31) << 7;
  const int bn = (swz >> 5) << 7;
  const int t = threadIdx.x, lane = t & 63, wave = t >> 6;
  const int lrow = lane & 15, lk = (lane >> 4) * 8;
  const int wr = wave * 32;
  const int r0 = t >> 2, c0 = (t & 3) * 8;

  f32x4 acc[2][8] = {};

#pragma unroll
  for (int is = 0; is < 2; ++is) {
    gload16(A + (size_t)(bm + is * 64 + r0) * HIDDEN + c0, &As[0][is * 2048 + t * 8]);
    gload16(B + (size_t)(bn + is * 64 + r0) * HIDDEN + c0, &Bs[0][is * 2048 + t * 8]);
  }
  __syncthreads();

  int p = 0;
  for (int kt = 0; kt < HIDDEN; kt += 32) {
    if (kt + 32 < HIDDEN) {
#pragma unroll
      for (int is = 0; is < 2; ++is) {
        gload16(A + (size_t)(bm + is * 64 + r0) * HIDDEN + kt + 32 + c0,
                &As[p ^ 1][is * 2048 + t * 8]);
        gload16(B + (size_t)(bn + is * 64 + r0) * HIDDEN + kt + 32 + c0,
                &Bs[p ^ 1][is * 2048 + t * 8]);
      }
    }
    bf16x8 af[2], bfv[8];
#pragma unroll
    for (int m = 0; m < 2; ++m)
      af[m] = __builtin_bit_cast(bf16x8,
          *reinterpret_cast<const u32x4*>(&As[p][(wr + m * 16 + lrow) * 32 + lk]));
#pragma unroll
    for (int n = 0; n < 8; ++n)
      bfv[n] = __builtin_bit_cast(bf16x8,
          *reinterpret_cast<const u32x4*>(&Bs[p][(n * 16 + lrow) * 32 + lk]));
#pragma unroll
    for (int n = 0; n < 8; ++n)
#pragma unroll
      for (int m = 0; m < 2; ++m)
        acc[m][n] = __builtin_amdgcn_mfma_f32_16x16x32_bf16(af[m], bfv[n], acc[m][n], 0, 0, 0);
    __syncthreads();
    p ^= 1;
  }

  const int rb = (lane >> 4) * 4;
#pragma unroll
  for (int m = 0; m < 2; ++m)
#pragma unroll
    for (int n = 0; n < 8; ++n)
#pragma unroll
      for (int q = 0; q < 4; ++q)
        C[(size_t)(bm + wr + m * 16 + rb + q) * HIDDEN + bn + n * 16 + lrow] =
            acc[m][n][q];
}

// ---------------- causal flash attention, KV-chunked for load balance -------
// 1280 blocks: (head, qtile, chunk). Chunk = balanced slice of the qtile's
// 2q+2 KV iterations, max 16. Single-chunk qtiles (q<8) write final output;
// multi-chunk write bf16 partial O + f32 (m,l) for the combine kernel.
__global__ __launch_bounds__(256, 2) void attn_kernel(const u16* __restrict__ Q,
                                                      const u16* __restrict__ Kg,
                                                      const u16* __restrict__ Vt,
                                                      u16* __restrict__ O,
                                                      u16* __restrict__ Opart,
                                                      float* __restrict__ Ml) {
  __shared__ u16 Ks[2][KVB * 128];
  __shared__ u16 Vs[2][128 * KVB];
  __shared__ u16 Ps[4][WQ * KVB];
  const int t = threadIdx.x;
  const int wave = t >> 6;
  const int lane = t & 63;
  const int lrow = lane & 15;
  const int lgrp = lane >> 4;

  // decode (head, qtile, chunk) — heavy chunks first
  const int g = blockIdx.x;           // 0..1279
  const int h = g / 80;
  const int e = 79 - (g - h * 80);
  int q, c, nc;
  if (e < 8)       { q = e;               c = 0;            nc = 1; }
  else if (e < 24) { q = 8 + ((e - 8) >> 1);  c = (e - 8) & 1;  nc = 2; }
  else if (e < 48) { q = 16 + (e - 24) / 3;   c = (e - 24) % 3; nc = 3; }
  else             { q = 24 + ((e - 48) >> 2); c = (e - 48) & 3; nc = 4; }
  const int total = 2 * q + 2;
  const int base = total / nc, rem = total - base * nc;
  const int it0 = c * base + (c < rem ? c : rem);
  const int it1 = it0 + base + (c < rem ? 1 : 0);

  const int qb0 = q * QBLK;
  const int qw = qb0 + wave * WQ;

  bf16x8 qf[2][4];
#pragma unroll
  for (int rowf = 0; rowf < 2; ++rowf)
#pragma unroll
    for (int kk = 0; kk < 4; ++kk)
      qf[rowf][kk] = __builtin_bit_cast(bf16x8, *reinterpret_cast<const u32x4*>(
          Q + (size_t)(qw + rowf * 16 + lrow) * HIDDEN + h * HDIM + kk * 32 + lgrp * 8));

  const u16* kgb[4]; const u16* vgb[4]; int kof[4], vof[4];
#pragma unroll
  for (int is = 0; is < 4; ++is) {
    int ch = is * 256 + t;
    int krow = ch >> 4, kslot = ch & 15;
    int kcol = ((kslot & 8) | ((kslot ^ krow) & 7)) * 8;
    kgb[is] = Kg + (size_t)krow * HIDDEN + h * HDIM + kcol;
    kof[is] = ch * 8;
    int vrow = ch >> 3, vslot = ch & 7;
    int vcol = ((vslot ^ vrow) & 7) * 8;
    vgb[is] = Vt + (size_t)(h * HDIM + vrow) * SEQ + vcol;
    vof[is] = ch * 8;
  }

  f32x4 acc[2][8] = {};
  float m2[2] = {-1e30f, -1e30f};
  float lsum[2] = {0.f, 0.f};

  // prologue: stage tile it0 into buffer 0
#pragma unroll
  for (int is = 0; is < 4; ++is) {
    gload16(kgb[is] + (size_t)(it0 * KVB) * HIDDEN, &Ks[0][kof[is]]);
    gload16(vgb[is] + it0 * KVB, &Vs[0][vof[is]]);
  }
  __syncthreads();

  int cur = 0;
  for (int bt = it0; bt < it1; ++bt) {
    const int t0 = bt * KVB;
    if (bt + 1 < it1) {
      const int t1 = (bt + 1) * KVB;
#pragma unroll
      for (int is = 0; is < 4; ++is) {
        gload16(kgb[is] + (size_t)t1 * HIDDEN, &Ks[cur ^ 1][kof[is]]);
        gload16(vgb[is] + t1, &Vs[cur ^ 1][vof[is]]);
      }
    }

    if (t0 <= qw + WQ - 1) {
      const bool need_mask = (t0 + KVB - 1 > qw);
      f32x4 sc[2][4] = {};
      __builtin_amdgcn_s_setprio(1);
#pragma unroll
      for (int kk = 0; kk < 4; ++kk) {
#pragma unroll
        for (int colf = 0; colf < 4; ++colf) {
          int trow = colf * 16 + lrow;
          int slot = kk * 4 + lgrp;
          bf16x8 kf = __builtin_bit_cast(bf16x8, *reinterpret_cast<const u32x4*>(
              &Ks[cur][trow * 128 + ((slot & 8) | ((slot ^ trow) & 7)) * 8]));
#pragma unroll
          for (int rowf = 0; rowf < 2; ++rowf)
            sc[rowf][colf] = __builtin_amdgcn_mfma_f32_16x16x32_bf16(
                kf, qf[rowf][kk], sc[rowf][colf], 0, 0, 0);
        }
      }
      __builtin_amdgcn_s_setprio(0);

      float pmax[2];
#pragma unroll
      for (int rowf = 0; rowf < 2; ++rowf) {
        const int qg = qw + rowf * 16 + lrow;
        float mx = -3.0e38f;
#pragma unroll
        for (int colf = 0; colf < 4; ++colf) {
          const int kvb0 = t0 + colf * 16 + lgrp * 4;
#pragma unroll
          for (int r = 0; r < 4; ++r) {
            float v = sc[rowf][colf][r] * SCL2;
            if (need_mask) v = (kvb0 + r <= qg) ? v : -1e30f;
            sc[rowf][colf][r] = v;
            mx = fmaxf(mx, v);
          }
        }
        mx = fmaxf(mx, __shfl_xor(mx, 16));
        mx = fmaxf(mx, __shfl_xor(mx, 32));
        pmax[rowf] = mx;
      }

      bool grow = (pmax[0] > m2[0] + 11.5f) || (pmax[1] > m2[1] + 11.5f);
      if (__any(grow)) {
#pragma unroll
        for (int rowf = 0; rowf < 2; ++rowf) {
          float mn = fmaxf(m2[rowf], pmax[rowf]);
          float sf = exp2f(m2[rowf] - mn);
          m2[rowf] = mn;
          lsum[rowf] *= sf;
#pragma unroll
          for (int r = 0; r < 4; ++r) {
            float sfr = __shfl(sf, (lane & 48) | (lgrp * 4 + r));
#pragma unroll
            for (int nn = 0; nn < 8; ++nn) acc[rowf][nn][r] *= sfr;
          }
        }
      }

#pragma unroll
      for (int rowf = 0; rowf < 2; ++rowf) {
        const int qq = rowf * 16 + lrow;
        float ps = 0.f;
#pragma unroll
        for (int colf = 0; colf < 4; ++colf) {
          float pv[4];
#pragma unroll
          for (int r = 0; r < 4; ++r) {
            pv[r] = exp2f(sc[rowf][colf][r] - m2[rowf]);
            ps += pv[r];
          }
          u32x2 pk2;
          pk2[0] = cvtpk(pv[0], pv[1]);
          pk2[1] = cvtpk(pv[2], pv[3]);
          const int kv = colf * 16 + lgrp * 4;
          const int sw = (kv >> 3) ^ (qq & 7);
          *reinterpret_cast<u32x2*>(&Ps[wave][qq * 64 + sw * 8 + (kv & 7)]) = pk2;
        }
        ps += __shfl_xor(ps, 16);
        ps += __shfl_xor(ps, 32);
        lsum[rowf] += ps;
      }

      __builtin_amdgcn_s_setprio(1);
#pragma unroll
      for (int ks = 0; ks < 2; ++ks) {
        bf16x8 pa[2];
#pragma unroll
        for (int rowf = 0; rowf < 2; ++rowf) {
          const int qq = rowf * 16 + lrow;
          const int sl = ks * 4 + lgrp;
          pa[rowf] = __builtin_bit_cast(bf16x8, *reinterpret_cast<const u32x4*>(
              &Ps[wave][qq * 64 + (sl ^ (qq & 7)) * 8]));
        }
#pragma unroll
        for (int nn = 0; nn < 8; ++nn) {
          const int d = nn * 16 + lrow;
          bf16x8 vb = __builtin_bit_cast(bf16x8, *reinterpret_cast<const u32x4*>(
              &Vs[cur][d * 64 + (((ks * 4 + lgrp) ^ d) & 7) * 8]));
#pragma unroll
          for (int rowf = 0; rowf < 2; ++rowf)
            acc[rowf][nn] = __builtin_amdgcn_mfma_f32_16x16x32_bf16(
                pa[rowf], vb, acc[rowf][nn], 0, 0, 0);
        }
      }
      __builtin_amdgcn_s_setprio(0);
    }

    __syncthreads();
    cur ^= 1;
  }

  if (nc == 1) {  // final output
#pragma unroll
    for (int rowf = 0; rowf < 2; ++rowf) {
      float inv[4];
#pragma unroll
      for (int r = 0; r < 4; ++r) {
        float lsr = __shfl(lsum[rowf], (lane & 48) | (lgrp * 4 + r));
        inv[r] = 1.0f / lsr;
      }
#pragma unroll
      for (int nn = 0; nn < 8; ++nn)
#pragma unroll
        for (int r = 0; r < 4; ++r) {
          int row = qw + rowf * 16 + lgrp * 4 + r;
          int col = h * HDIM + nn * 16 + lrow;
          O[(size_t)row * HIDDEN + col] = f2bf(acc[rowf][nn][r] * inv[r]);
        }
    }
  } else {  // partial: unnormalized O (bf16) + per-row m,l (f32)
    const int slot = h * 72 + cumq(q) + c;
    u16* Op = Opart + (size_t)slot * (QBLK * HDIM);
    float* ml = Ml + (size_t)slot * 256;
#pragma unroll
    for (int rowf = 0; rowf < 2; ++rowf) {
#pragma unroll
      for (int nn = 0; nn < 8; ++nn)
#pragma unroll
        for (int r = 0; r < 4; ++r) {
          int rl = wave * 32 + rowf * 16 + lgrp * 4 + r;
          Op[rl * HDIM + nn * 16 + lrow] = f2bf(acc[rowf][nn][r]);
        }
      if (lgrp == 0) {
        int rl = wave * 32 + rowf * 16 + lrow;
        ml[rl] = m2[rowf];
        ml[128 + rl] = lsum[rowf];
      }
    }
  }
}

// ---------------- combine partial chunks ----------------
// grid 384: (head, qtile>=8). 256 threads: 2 threads/row x 64 dims.
__global__ __launch_bounds__(256) void combine_kernel(const u16* __restrict__ Opart,
                                                      const float* __restrict__ Ml,
                                                      u16* __restrict__ O) {
  const int bid = blockIdx.x;
  const int h = bid / 24;
  const int q = 8 + bid % 24;
  const int nc = q / 8 + 1;
  const int sbase = h * 72 + cumq(q);
  const int r = threadIdx.x >> 1;
  const int d0 = (threadIdx.x & 1) * 64;

  float w[4], l = 0.f, M = -3.0e38f;
#pragma unroll
  for (int c = 0; c < 4; ++c)
    if (c < nc) M = fmaxf(M, Ml[(size_t)(sbase + c) * 256 + r]);
#pragma unroll
  for (int c = 0; c < 4; ++c)
    if (c < nc) {
      w[c] = exp2f(Ml[(size_t)(sbase + c) * 256 + r] - M);
      l += w[c] * Ml[(size_t)(sbase + c) * 256 + 128 + r];
    }
  const float inv = 1.0f / l;

  for (int dd = 0; dd < 64; dd += 8) {
    float a8[8] = {};
#pragma unroll
    for (int c = 0; c < 4; ++c)
      if (c < nc) {
        u16x8 v = *reinterpret_cast<const u16x8*>(
            Opart + (size_t)(sbase + c) * (QBLK * HDIM) + r * HDIM + d0 + dd);
#pragma unroll
        for (int j = 0; j < 8; ++j) a8[j] += w[c] * bf2f(v[j]);
      }
    u16x8 o8;
#pragma unroll
    for (int j = 0; j < 8; ++j) o8[j] = f2bf(a8[j] * inv);
    *reinterpret_cast<u16x8*>(
        &O[(size_t)(q * QBLK + r) * HIDDEN + h * HDIM + d0 + dd]) = o8;
  }
}

// ---------------- launch ----------------
extern "C" void kernel_launch(void* const* d_in, const int* in_sizes, int n_in,
                              void* d_out, int out_size, void* d_ws, size_t ws_size,
                              hipStream_t stream) {
  const float* X  = (const float*)d_in[0];
  const float* Wq = (const float*)d_in[1];
  const float* Wk = (const float*)d_in[2];
  const float* Wv = (const float*)d_in[3];
  const float* Wo = (const float*)d_in[4];
  float* out = (float*)d_out;

  u16* ws = (u16*)d_ws;
  const size_t SH = (size_t)SEQ * HIDDEN;
  const size_t HH = (size_t)HIDDEN * HIDDEN;
  u16* Xb  = ws;
  u16* Wqb = Xb + SH;
  u16* Wkb = Wqb + HH;
  u16* Wvb = Wkb + HH;
  u16* Wob = Wvb + HH;
  u16* Qb  = Wob + HH;
  u16* Kb  = Qb + SH;
  u16* Vtb = Kb + SH;   // V^T: [HIDDEN][SEQ]
  u16* Cb  = Vtb + SH;

  // attention partials reuse the dead Xb..Wvb region (alive only pre-attn):
  // 1152 slots x 16384 u16 (37.7 MB) + 1152 x 256 f32 (1.2 MB) < 41.9 MB
  u16* Opart = ws;
  float* Ml = (float*)(ws + (size_t)1152 * 16384);

  cvt5<<<(int)((SH + 4 * HH) / 2048), 256, 0, stream>>>(X, Wq, Wk, Wv, Wo, ws);

  gemm_qkv<<<1536, 256, 0, stream>>>(Xb, Wqb, Wkb, Wvb, Qb, Kb, Vtb);

  attn_kernel<<<1280, 256, 0, stream>>>(Qb, Kb, Vtb, Cb, Opart, Ml);
  combine_kernel<<<384, 256, 0, stream>>>(Opart, Ml, Cb);

  gemm_out<<<512, 256, 0, stream>>>(Cb, Wob, out);
}